// Round 1
// baseline (410.488 us; speedup 1.0000x reference)
//
#include <hip/hip_runtime.h>

#define NUMA 5
#define NCLS 80
#define AL 85          // 80 + 4 + 1
#define HW 361         // 19*19
#define NBOX 1805      // 5*361
#define NBATCH 128
#define NPAD 2048
#define K2T 256

// ---------------------------------------------------------------------------
// Kernel 1: decode.  pred [B, 425, 19, 19] -> det [B, 1805, 7] written to out
// det columns: [obj, bx, by, bw, bh, cid, prob]
// box index r = a*361 + j*19 + i  (matches reshape(B, NUM*h*w, 7))
// ---------------------------------------------------------------------------
__global__ __launch_bounds__(256) void decode_kernel(
    const float* __restrict__ pred,
    const float* __restrict__ anchors,
    float* __restrict__ det)
{
#pragma clang fp contract(off)
    int id = blockIdx.x * blockDim.x + threadIdx.x;
    if (id >= NBATCH * NBOX) return;
    int b = id / NBOX;
    int r = id - b * NBOX;
    int a = r / HW;
    int s = r - a * HW;
    int ci = s % 19;      // column (i, along W)
    int cj = s / 19;      // row    (j, along H)

    const float* base = pred + ((size_t)(b * (NUMA * AL) + a * AL) * HW + s);
    float tx  = base[0 * HW];
    float ty  = base[1 * HW];
    float tw  = base[2 * HW];
    float th  = base[3 * HW];
    float obj = base[4 * HW];

    // argmax over 80 classes, first-occurrence semantics (strict >)
    float cmax = base[5 * HW];
    int karg = 0;
#pragma unroll 4
    for (int k = 1; k < NCLS; ++k) {
        float c = base[(5 + k) * HW];
        if (c > cmax) { cmax = c; karg = k; }
    }

    float bx = (tx + (float)ci) / 19.0f;
    float by = (ty + (float)cj) / 19.0f;
    float aw = anchors[2 * a];
    float ah = anchors[2 * a + 1];
    float bw = expf(tw) * (aw / 19.0f);
    float bh = expf(th) * (ah / 19.0f);
    float prob = cmax * obj;
    float cid  = (float)karg;

    float* o = det + (size_t)(b * NBOX + r) * 7;
    o[0] = obj; o[1] = bx; o[2] = by; o[3] = bw; o[4] = bh; o[5] = cid; o[6] = prob;
}

// ---------------------------------------------------------------------------
// Kernel 2: per-image stable sort (desc by obj) + greedy NMS + filters.
// One block per image; operates in-place on det (= d_out).
// ---------------------------------------------------------------------------
__global__ __launch_bounds__(K2T) void nms_kernel(float* __restrict__ det)
{
#pragma clang fp contract(off)
    // Region R: first holds the 2048 sort keys (16384 B), later reused for
    // the 5 box arrays x1,y1,x2,y2,area (36100 B).
    __shared__ alignas(16) char Rbuf[5 * NBOX * 4 + 16];
    unsigned long long* keys = reinterpret_cast<unsigned long long*>(Rbuf);
    float* X1 = reinterpret_cast<float*>(Rbuf);
    float* Y1 = X1 + NBOX;
    float* X2 = X1 + 2 * NBOX;
    float* Y2 = X1 + 3 * NBOX;
    float* AR = X1 + 4 * NBOX;

    __shared__ float s_obj[NBOX];          // running scores (zeroed on suppress)
    __shared__ unsigned short order[NBOX]; // sorted-rank -> original index
    __shared__ int num_obj_sh;

    const int b = blockIdx.x;
    const int tid = threadIdx.x;
    float* detb = det + (size_t)b * NBOX * 7;

    // --- 1. build sort keys: (obj_bits << 32) | (2047 - idx)  (stable desc) ---
    for (int n = tid; n < NPAD; n += K2T) {
        if (n < NBOX) {
            unsigned ob = __float_as_uint(detb[n * 7 + 0]);   // obj in [0,1): sign bit 0
            keys[n] = ((unsigned long long)ob << 32) | (unsigned long long)(2047 - n);
        } else {
            keys[n] = 0ull;  // pads sort to the end (all real keys > 0)
        }
    }
    if (tid == 0) num_obj_sh = 0;
    __syncthreads();

    // --- 2. bitonic sort, descending ---
    for (unsigned k = 2; k <= NPAD; k <<= 1) {
        for (unsigned j = k >> 1; j > 0; j >>= 1) {
            for (unsigned idx = tid; idx < NPAD; idx += K2T) {
                unsigned ixj = idx ^ j;
                if (ixj > idx) {
                    unsigned long long av = keys[idx], bv = keys[ixj];
                    bool up = ((idx & k) == 0);
                    if (up ? (av < bv) : (av > bv)) { keys[idx] = bv; keys[ixj] = av; }
                }
            }
            __syncthreads();
        }
    }

    // --- 3. extract order, s (=sorted obj), num_obj ---
    int cnt = 0;
    for (int r = tid; r < NBOX; r += K2T) {
        unsigned long long kk = keys[r];
        order[r] = (unsigned short)(2047u - (unsigned)(kk & 0xffffffffu));
        float ob = __uint_as_float((unsigned)(kk >> 32));
        s_obj[r] = ob;
        cnt += (ob > 0.5f) ? 1 : 0;
    }
    atomicAdd(&num_obj_sh, cnt);
    __syncthreads();               // keys fully read; num_obj final
    const int num_obj = num_obj_sh;

    // --- 4. gather boxes into sorted-order arrays (overwrites keys region) ---
    for (int r = tid; r < NBOX; r += K2T) {
        const float* row = detb + (int)order[r] * 7;
        float bx = row[1], by = row[2], bw = row[3], bh = row[4];
        X1[r] = bx - 0.5f * bw;
        X2[r] = bx + 0.5f * bw;
        Y1[r] = by - 0.5f * bh;
        Y2[r] = by + 0.5f * bh;
        AR[r] = bw * bh;
    }
    __syncthreads();

    // --- 5. greedy serial NMS (sequential dependency over i) ---
    for (int i = 0; i < num_obj; ++i) {
        if (s_obj[i] > 0.01f) {     // still alive -> suppresses later boxes
            float xi1 = X1[i], xi2 = X2[i], yi1 = Y1[i], yi2 = Y2[i], ai = AR[i];
            for (int j = i + 1 + tid; j < num_obj; j += K2T) {
                float iw = fminf(X2[j], xi2) - fmaxf(X1[j], xi1);
                iw = fmaxf(iw, 0.0f);
                float ih = fminf(Y2[j], yi2) - fmaxf(Y1[j], yi1);
                ih = fmaxf(ih, 0.0f);
                float inter = iw * ih;
                float iou = inter / ((AR[j] + ai) - inter);   // exact ref arithmetic
                if (iou >= 0.45f) s_obj[j] = 0.0f;
            }
        }
        __syncthreads();
    }

    // --- 6. epilogue: read rows (regs), barrier, write filtered output ---
    float v0[8], v1[8], v2[8], v3[8], v4[8], v5[8], v6[8];
    float msk[8];
#pragma unroll
    for (int c = 0; c < 8; ++c) {
        int r = tid + c * K2T;
        if (r < NBOX) {
            const float* row = detb + (int)order[r] * 7;
            float obj = row[0], bx = row[1], by = row[2], bw = row[3];
            float bh = row[4], cid = row[5], prob = row[6];
            bool keep = (r < num_obj) && (s_obj[r] > 0.01f) && (r != num_obj - 1);
            float p = prob * ((prob > 0.1f) ? 1.0f : 0.0f);
            bool fin = keep && (p > 0.01f) && (bw * bw > 0.0004f);
            v0[c] = obj; v1[c] = bx; v2[c] = by; v3[c] = bw; v4[c] = bh;
            v5[c] = cid; v6[c] = p;
            msk[c] = fin ? 1.0f : 0.0f;
        }
    }
    __syncthreads();   // all reads of det complete before any in-place write
#pragma unroll
    for (int c = 0; c < 8; ++c) {
        int r = tid + c * K2T;
        if (r < NBOX) {
            float* o = detb + r * 7;
            o[0] = v0[c] * msk[c];
            o[1] = v1[c] * msk[c];
            o[2] = v2[c] * msk[c];
            o[3] = v3[c] * msk[c];
            o[4] = v4[c] * msk[c];
            o[5] = v5[c] * msk[c];
            o[6] = v6[c] * msk[c];
        }
    }
}

extern "C" void kernel_launch(void* const* d_in, const int* in_sizes, int n_in,
                              void* d_out, int out_size, void* d_ws, size_t ws_size,
                              hipStream_t stream)
{
    const float* pred    = (const float*)d_in[0];
    const float* anchors = (const float*)d_in[1];
    float* out = (float*)d_out;

    int total = NBATCH * NBOX;
    int blocks = (total + 255) / 256;
    decode_kernel<<<blocks, 256, 0, stream>>>(pred, anchors, out);
    nms_kernel<<<NBATCH, K2T, 0, stream>>>(out);
}

// Round 2
// 398.072 us; speedup vs baseline: 1.0312x; 1.0312x over previous
//
#include <hip/hip_runtime.h>

#define NUMA 5
#define NCLS 80
#define AL 85          // 80 + 4 + 1
#define HW 361         // 19*19
#define NBOX 1805      // 5*361
#define NBATCH 128
#define NPAD 2048
#define K2T 256
#define MCAP 1024      // register-path cap on num_obj (expected ~902 +/- 21)
#define NCHUNK 16      // MCAP / 64

// ---------------------------------------------------------------------------
// Kernel 1: decode.  pred [B, 425, 19, 19] -> det [B, 1805, 7] written to out
// det columns: [obj, bx, by, bw, bh, cid, prob]
// ---------------------------------------------------------------------------
__global__ __launch_bounds__(256) void decode_kernel(
    const float* __restrict__ pred,
    const float* __restrict__ anchors,
    float* __restrict__ det)
{
#pragma clang fp contract(off)
    int id = blockIdx.x * blockDim.x + threadIdx.x;
    if (id >= NBATCH * NBOX) return;
    int b = id / NBOX;
    int r = id - b * NBOX;
    int a = r / HW;
    int s = r - a * HW;
    int ci = s % 19;
    int cj = s / 19;

    const float* base = pred + ((size_t)(b * (NUMA * AL) + a * AL) * HW + s);
    float tx  = base[0 * HW];
    float ty  = base[1 * HW];
    float tw  = base[2 * HW];
    float th  = base[3 * HW];
    float obj = base[4 * HW];

    float cmax = base[5 * HW];
    int karg = 0;
#pragma unroll 4
    for (int k = 1; k < NCLS; ++k) {
        float c = base[(5 + k) * HW];
        if (c > cmax) { cmax = c; karg = k; }
    }

    float bx = (tx + (float)ci) / 19.0f;
    float by = (ty + (float)cj) / 19.0f;
    float aw = anchors[2 * a];
    float ah = anchors[2 * a + 1];
    float bw = expf(tw) * (aw / 19.0f);
    float bh = expf(th) * (ah / 19.0f);
    float prob = cmax * obj;
    float cid  = (float)karg;

    float* o = det + (size_t)(b * NBOX + r) * 7;
    o[0] = obj; o[1] = bx; o[2] = by; o[3] = bw; o[4] = bh; o[5] = cid; o[6] = prob;
}

// ---------------------------------------------------------------------------
// Kernel 2: per-image stable sort (desc by obj) + greedy NMS + filters.
// One block per image; operates in-place on det (= d_out).
// ---------------------------------------------------------------------------
__global__ __launch_bounds__(K2T) void nms_kernel(float* __restrict__ det)
{
#pragma clang fp contract(off)
    __shared__ alignas(16) union {
        unsigned long long keys[NPAD];      // 16 KB during sort
        struct {
            float4 q[MCAP];                 // (x1,y1,x2,y2) per sorted rank
            float  area[MCAP];
        } box;                              // 20 KB after sort
    } U;
    __shared__ float s_obj[NBOX];           // running scores (0 = suppressed)
    __shared__ unsigned short order[NBOX];  // sorted rank -> original index
    __shared__ int num_obj_sh;

    const int b = blockIdx.x;
    const int tid = threadIdx.x;
    float* detb = det + (size_t)b * NBOX * 7;

    // --- 1. build stable-descending sort keys: (obj_bits<<32) | (2047-idx) ---
    for (int n = tid; n < NPAD; n += K2T) {
        if (n < NBOX) {
            unsigned ob = __float_as_uint(detb[n * 7 + 0]);  // obj in [0,1): sign bit 0
            U.keys[n] = ((unsigned long long)ob << 32) | (unsigned long long)(2047 - n);
        } else {
            U.keys[n] = 0ull;
        }
    }
    if (tid == 0) num_obj_sh = 0;
    __syncthreads();

    // --- 2. bitonic sort, descending ---
    for (unsigned k = 2; k <= NPAD; k <<= 1) {
        for (unsigned j = k >> 1; j > 0; j >>= 1) {
            for (unsigned idx = tid; idx < NPAD; idx += K2T) {
                unsigned ixj = idx ^ j;
                if (ixj > idx) {
                    unsigned long long av = U.keys[idx], bv = U.keys[ixj];
                    bool up = ((idx & k) == 0);
                    if (up ? (av < bv) : (av > bv)) { U.keys[idx] = bv; U.keys[ixj] = av; }
                }
            }
            __syncthreads();
        }
    }

    // --- 3. extract order, sorted obj, num_obj ---
    int cnt = 0;
    for (int r = tid; r < NBOX; r += K2T) {
        unsigned long long kk = U.keys[r];
        order[r] = (unsigned short)(2047u - (unsigned)(kk & 0xffffffffu));
        float ob = __uint_as_float((unsigned)(kk >> 32));
        s_obj[r] = ob;
        cnt += (ob > 0.5f) ? 1 : 0;
    }
    atomicAdd(&num_obj_sh, cnt);
    __syncthreads();                 // keys fully consumed; num_obj final
    const int num_obj = num_obj_sh;
    const int M = (num_obj < MCAP) ? num_obj : MCAP;

    if (num_obj <= MCAP) {
        // --- 4. gather packed boxes for ranks < M (overwrites keys region) ---
        for (int r = tid; r < M; r += K2T) {
            const float* row = detb + (int)order[r] * 7;
            float bx = row[1], by = row[2], bw = row[3], bh = row[4];
            float x1 = bx - 0.5f * bw;
            float x2 = bx + 0.5f * bw;
            float y1 = by - 0.5f * bh;
            float y2 = by + 0.5f * bh;
            U.box.q[r] = make_float4(x1, y1, x2, y2);
            U.box.area[r] = bw * bh;
        }
        __syncthreads();

        // --- 5. greedy NMS, wave 0 only, all state in registers ---
        if (tid < 64) {
            const int lane = tid;
            float4 q[NCHUNK];
            float  ar[NCHUNK];
            unsigned long long w[NCHUNK];   // removed bits, uniform across wave
#pragma unroll
            for (int c = 0; c < NCHUNK; ++c) {
                int j = c * 64 + lane;
                if (j < M) { q[c] = U.box.q[j]; ar[c] = U.box.area[j]; }
                else       { q[c] = make_float4(3e9f, 3e9f, 3e9f, 3e9f); ar[c] = 1.0f; }
                w[c] = 0ull;
            }
#pragma unroll
            for (int c = 0; c < NCHUNK; ++c) {
                const int base = c * 64;
                if (base < M) {
                    int top = M - base;
                    unsigned long long chunkmask =
                        (top >= 64) ? ~0ull : ((1ull << top) - 1ull);
                    unsigned long long done = 0ull;
                    while (true) {
                        unsigned long long avail = chunkmask & ~w[c] & ~done;
                        if (avail == 0ull) break;
                        int t = (int)__builtin_ctzll(avail);   // next alive rank in chunk
                        done |= (t >= 63) ? ~0ull : ((1ull << (t + 1)) - 1ull);
                        int i = base + t;
                        float4 qi = U.box.q[i];                // LDS broadcast
                        float  ai = U.box.area[i];
#pragma unroll
                        for (int c2 = 0; c2 < NCHUNK; ++c2) {
                            if (c2 >= c) {
                                if (c2 * 64 < M) {
                                    float iw = fminf(q[c2].z, qi.z) - fmaxf(q[c2].x, qi.x);
                                    iw = fmaxf(iw, 0.0f);
                                    float ih = fminf(q[c2].w, qi.w) - fmaxf(q[c2].y, qi.y);
                                    ih = fmaxf(ih, 0.0f);
                                    float inter = iw * ih;
                                    float iou = inter / ((ar[c2] + ai) - inter); // exact ref arith
                                    bool supp = (iou >= 0.45f) &&
                                                ((c2 > c) || (lane > t));
                                    unsigned long long bb = __ballot(supp);
                                    w[c2] |= bb;
                                }
                            }
                        }
                    }
                }
            }
            // write removals back to s_obj
#pragma unroll
            for (int c = 0; c < NCHUNK; ++c) {
                int j = c * 64 + lane;
                if (j < M && ((w[c] >> lane) & 1ull)) s_obj[j] = 0.0f;
            }
        }
        __syncthreads();
    } else {
        // --- fallback (num_obj > MCAP; statistically unreachable, kept for
        //     correctness safety): original barrier-serial loop on detb rows ---
        for (int i = 0; i < num_obj; ++i) {
            if (s_obj[i] > 0.01f) {
                const float* ri = detb + (int)order[i] * 7;
                float bxi = ri[1], byi = ri[2], bwi = ri[3], bhi = ri[4];
                float xi1 = bxi - 0.5f * bwi, xi2 = bxi + 0.5f * bwi;
                float yi1 = byi - 0.5f * bhi, yi2 = byi + 0.5f * bhi;
                float ai = bwi * bhi;
                for (int j = i + 1 + tid; j < num_obj; j += K2T) {
                    const float* rj = detb + (int)order[j] * 7;
                    float bxj = rj[1], byj = rj[2], bwj = rj[3], bhj = rj[4];
                    float x1j = bxj - 0.5f * bwj, x2j = bxj + 0.5f * bwj;
                    float y1j = byj - 0.5f * bhj, y2j = byj + 0.5f * bhj;
                    float aj = bwj * bhj;
                    float iw = fmaxf(fminf(x2j, xi2) - fmaxf(x1j, xi1), 0.0f);
                    float ih = fmaxf(fminf(y2j, yi2) - fmaxf(y1j, yi1), 0.0f);
                    float inter = iw * ih;
                    float iou = inter / ((aj + ai) - inter);
                    if (iou >= 0.45f) s_obj[j] = 0.0f;
                }
            }
            __syncthreads();
        }
    }

    // --- 6. epilogue: read rows (regs), barrier, write filtered output ---
    float v0[8], v1[8], v2[8], v3[8], v4[8], v5[8], v6[8];
    float msk[8];
#pragma unroll
    for (int c = 0; c < 8; ++c) {
        int r = tid + c * K2T;
        if (r < NBOX) {
            const float* row = detb + (int)order[r] * 7;
            float obj = row[0], bx = row[1], by = row[2], bw = row[3];
            float bh = row[4], cid = row[5], prob = row[6];
            bool keep = (r < num_obj) && (s_obj[r] > 0.01f) && (r != num_obj - 1);
            float p = prob * ((prob > 0.1f) ? 1.0f : 0.0f);
            bool fin = keep && (p > 0.01f) && (bw * bw > 0.0004f);
            v0[c] = obj; v1[c] = bx; v2[c] = by; v3[c] = bw; v4[c] = bh;
            v5[c] = cid; v6[c] = p;
            msk[c] = fin ? 1.0f : 0.0f;
        }
    }
    __syncthreads();   // all reads of det complete before any in-place write
#pragma unroll
    for (int c = 0; c < 8; ++c) {
        int r = tid + c * K2T;
        if (r < NBOX) {
            float* o = detb + r * 7;
            o[0] = v0[c] * msk[c];
            o[1] = v1[c] * msk[c];
            o[2] = v2[c] * msk[c];
            o[3] = v3[c] * msk[c];
            o[4] = v4[c] * msk[c];
            o[5] = v5[c] * msk[c];
            o[6] = v6[c] * msk[c];
        }
    }
}

extern "C" void kernel_launch(void* const* d_in, const int* in_sizes, int n_in,
                              void* d_out, int out_size, void* d_ws, size_t ws_size,
                              hipStream_t stream)
{
    const float* pred    = (const float*)d_in[0];
    const float* anchors = (const float*)d_in[1];
    float* out = (float*)d_out;

    int total = NBATCH * NBOX;
    int blocks = (total + 255) / 256;
    decode_kernel<<<blocks, 256, 0, stream>>>(pred, anchors, out);
    nms_kernel<<<NBATCH, K2T, 0, stream>>>(out);
}